// Round 1
// baseline (238.393 us; speedup 1.0000x reference)
//
#include <hip/hip_runtime.h>
#include <math.h>

using short8 = __attribute__((ext_vector_type(8))) short;
using f32x4 = __attribute__((ext_vector_type(4))) float;

#define CAP 48   // edge-bucket capacity; P(Poisson(6) >= 48) ~ 1e-30

__device__ inline short f2bf(float f) {
    unsigned u = __builtin_bit_cast(unsigned, f);
    unsigned r = (u + 0x7fffu + ((u >> 16) & 1u)) >> 16;
    return (short)r;
}
__device__ inline float bf2f(short s) {
    unsigned u = ((unsigned)(unsigned short)s) << 16;
    return __builtin_bit_cast(float, u);
}

// ---------------- fused prep: x->bf16, W transposes, edge bucketing ----------------
// deg[] must be zeroed (memsetAsync) before this kernel.

__global__ void prep_kernel(const float* __restrict__ x, const float* __restrict__ W1,
                            const float* __restrict__ W2, const float* __restrict__ Wc,
                            const int* __restrict__ src, const int* __restrict__ dst,
                            short* __restrict__ xb, short* __restrict__ Wt1,
                            short* __restrict__ Wt2, short* __restrict__ Wtc,
                            int* __restrict__ deg, int* __restrict__ eslot,
                            int n, int e) {
    int idx = blockIdx.x * blockDim.x + threadIdx.x;
    const int nx8 = n * 16;                      // N*128/8 groups of 8
    if (idx < nx8) {
        const float4* p = (const float4*)x + (size_t)idx * 2;
        float4 v0 = p[0], v1 = p[1];
        short8 o;
        o[0] = f2bf(v0.x); o[1] = f2bf(v0.y); o[2] = f2bf(v0.z); o[3] = f2bf(v0.w);
        o[4] = f2bf(v1.x); o[5] = f2bf(v1.y); o[6] = f2bf(v1.z); o[7] = f2bf(v1.w);
        ((short8*)xb)[idx] = o;
        return;
    }
    idx -= nx8;
    if (idx < 128 * 256) {                       // W1: K=128, N=256
        int k = idx >> 8, c = idx & 255;
        Wt1[c * 128 + k] = f2bf(W1[idx]);
        return;
    }
    idx -= 128 * 256;
    if (idx < 256 * 256) {                       // W2: K=256, N=256
        int k = idx >> 8, c = idx & 255;
        Wt2[c * 256 + k] = f2bf(W2[idx]);
        return;
    }
    idx -= 256 * 256;
    if (idx < 256 * 32) {                        // Wc: K=256, N=32
        int k = idx >> 5, c = idx & 31;
        Wtc[c * 256 + k] = f2bf(Wc[idx]);
        return;
    }
    idx -= 256 * 32;
    if (idx < e) {                               // edge bucketing
        int d = dst[idx], s = src[idx];
        int pos = atomicAdd(&deg[d], 1);
        if (pos < CAP) eslot[(size_t)d * CAP + pos] = s;
    }
}

// ---------------- bf16 MFMA GEMM 128x128 ----------------
// 4 waves; wave computes 64x64 via 4x4 of 16x16x32 MFMAs. LDS rows padded
// to 40 shorts (80B) -> max 2-way bank aliasing (free).
// SCALE_DINV: multiply the (relu'd) output row by rsqrt(deg[row]+1) so the
// next gather can be a pure unweighted sum (symmetric-norm pre-scaling).

template<bool RELU_BF16OUT, bool SCALE_DINV>
__global__ __launch_bounds__(256) void mfma_gemm128_kernel(
    const short* __restrict__ A, const short* __restrict__ Wt,
    const float* __restrict__ bias, void* __restrict__ Cout,
    const int* __restrict__ deg,
    int M, int K, int NC)
{
    __shared__ short As[128 * 40];
    __shared__ short Bs[128 * 40];

    const int tid = threadIdx.x;
    const int wave = tid >> 6, lane = tid & 63;
    const int m0 = blockIdx.y * 128, n0 = blockIdx.x * 128;
    const int wm = (wave >> 1) * 64, wn = (wave & 1) * 64;

    const int sar = tid >> 2;
    const int sak = (tid & 3) * 8;
    int ga0 = m0 + sar;      if (ga0 >= M) ga0 = M - 1;
    int ga1 = m0 + 64 + sar; if (ga1 >= M) ga1 = M - 1;
    int gb0 = n0 + sar;      if (gb0 >= NC) gb0 = NC - 1;
    int gb1 = n0 + 64 + sar; if (gb1 >= NC) gb1 = NC - 1;
    const short* pa0 = A + (size_t)ga0 * K + sak;
    const short* pa1 = A + (size_t)ga1 * K + sak;
    const short* pb0 = Wt + (size_t)gb0 * K + sak;
    const short* pb1 = Wt + (size_t)gb1 * K + sak;

    const int lw0 = sar * 40 + sak;
    const int lw1 = (64 + sar) * 40 + sak;

    f32x4 acc[4][4] = {};
    const int fr = lane & 15;
    const int fk = (lane >> 4) * 8;

    for (int k0 = 0; k0 < K; k0 += 32) {
        short8 va0 = *(const short8*)(pa0 + k0);
        short8 va1 = *(const short8*)(pa1 + k0);
        short8 vb0 = *(const short8*)(pb0 + k0);
        short8 vb1 = *(const short8*)(pb1 + k0);
        __syncthreads();
        *(short8*)&As[lw0] = va0;
        *(short8*)&As[lw1] = va1;
        *(short8*)&Bs[lw0] = vb0;
        *(short8*)&Bs[lw1] = vb1;
        __syncthreads();

        short8 af[4], bfv[4];
        #pragma unroll
        for (int mt = 0; mt < 4; ++mt)
            af[mt] = *(const short8*)&As[(wm + mt * 16 + fr) * 40 + fk];
        #pragma unroll
        for (int nt = 0; nt < 4; ++nt)
            bfv[nt] = *(const short8*)&Bs[(wn + nt * 16 + fr) * 40 + fk];

        #pragma unroll
        for (int mt = 0; mt < 4; ++mt)
            #pragma unroll
            for (int nt = 0; nt < 4; ++nt)
                acc[mt][nt] = __builtin_amdgcn_mfma_f32_16x16x32_bf16(
                    af[mt], bfv[nt], acc[mt][nt], 0, 0, 0);
    }

    #pragma unroll
    for (int mt = 0; mt < 4; ++mt) {
        #pragma unroll
        for (int r = 0; r < 4; ++r) {
            int grow = m0 + wm + mt * 16 + (lane >> 4) * 4 + r;
            if (grow >= M) continue;
            float rowscale = 1.0f;
            if (SCALE_DINV)
                rowscale = rsqrtf((float)deg[grow] + 1.0f);
            #pragma unroll
            for (int nt = 0; nt < 4; ++nt) {
                int gcol = n0 + wn + nt * 16 + (lane & 15);
                if (gcol < NC) {
                    float v = acc[mt][nt][r] + bias[gcol];
                    if (RELU_BF16OUT)
                        ((short*)Cout)[(size_t)grow * NC + gcol] =
                            f2bf(fmaxf(v, 0.f) * rowscale);
                    else
                        ((float*)Cout)[(size_t)grow * NC + gcol] = v;
                }
            }
        }
    }
}

// ---------------- classifier GEMM: 128x32 block, 2 waves, NC=32 ----------------

__global__ __launch_bounds__(128) void mfma_gemmc_kernel(
    const short* __restrict__ A, const short* __restrict__ Wt,
    const float* __restrict__ bias, float* __restrict__ Cout,
    int M, int K)
{
    const int NC = 32;
    __shared__ short As[128 * 40];
    __shared__ short Bs[32 * 40];

    const int tid = threadIdx.x;
    const int wave = tid >> 6, lane = tid & 63;
    const int m0 = blockIdx.x * 128;
    const int wm = wave * 64;

    const int sar = tid >> 2;          // 0..31
    const int sak = (tid & 3) * 8;
    int gr0 = m0 + sar;       if (gr0 >= M) gr0 = M - 1;
    int gr1 = m0 + 32 + sar;  if (gr1 >= M) gr1 = M - 1;
    int gr2 = m0 + 64 + sar;  if (gr2 >= M) gr2 = M - 1;
    int gr3 = m0 + 96 + sar;  if (gr3 >= M) gr3 = M - 1;
    const short* pa0 = A + (size_t)gr0 * K + sak;
    const short* pa1 = A + (size_t)gr1 * K + sak;
    const short* pa2 = A + (size_t)gr2 * K + sak;
    const short* pa3 = A + (size_t)gr3 * K + sak;
    const short* pb  = Wt + (size_t)sar * K + sak;

    f32x4 acc[4][2] = {};
    const int fr = lane & 15;
    const int fk = (lane >> 4) * 8;

    for (int k0 = 0; k0 < K; k0 += 32) {
        short8 va0 = *(const short8*)(pa0 + k0);
        short8 va1 = *(const short8*)(pa1 + k0);
        short8 va2 = *(const short8*)(pa2 + k0);
        short8 va3 = *(const short8*)(pa3 + k0);
        short8 vb  = *(const short8*)(pb + k0);
        __syncthreads();
        *(short8*)&As[(sar)       * 40 + sak] = va0;
        *(short8*)&As[(32 + sar)  * 40 + sak] = va1;
        *(short8*)&As[(64 + sar)  * 40 + sak] = va2;
        *(short8*)&As[(96 + sar)  * 40 + sak] = va3;
        *(short8*)&Bs[sar * 40 + sak] = vb;
        __syncthreads();

        short8 af[4], bfv[2];
        #pragma unroll
        for (int mt = 0; mt < 4; ++mt)
            af[mt] = *(const short8*)&As[(wm + mt * 16 + fr) * 40 + fk];
        #pragma unroll
        for (int nt = 0; nt < 2; ++nt)
            bfv[nt] = *(const short8*)&Bs[(nt * 16 + fr) * 40 + fk];

        #pragma unroll
        for (int mt = 0; mt < 4; ++mt)
            #pragma unroll
            for (int nt = 0; nt < 2; ++nt)
                acc[mt][nt] = __builtin_amdgcn_mfma_f32_16x16x32_bf16(
                    af[mt], bfv[nt], acc[mt][nt], 0, 0, 0);
    }

    #pragma unroll
    for (int mt = 0; mt < 4; ++mt) {
        #pragma unroll
        for (int nt = 0; nt < 2; ++nt) {
            #pragma unroll
            for (int r = 0; r < 4; ++r) {
                int grow = m0 + wm + mt * 16 + (lane >> 4) * 4 + r;
                int gcol = nt * 16 + (lane & 15);
                if (grow < M)
                    Cout[(size_t)grow * NC + gcol] = acc[mt][nt][r] + bias[gcol];
            }
        }
    }
}

// ---------------- bucket gather, padded 8-wide rounds ----------------
// LPN lanes per node, 8 feats (16B) per lane. Edges processed in
// ceil(deg/8) fully-parallel octets: one bucket round-trip + one row-load
// round-trip covers deg<=8 (~84% of nodes) in a single iteration.
//
// PRESCALED=false (layer 1): input rows are raw; per-edge weight
//   dinv[dst]*dinv[src] with dinv[src]=rsqrt(deg[src]+1) looked up per edge.
//   Self term weighted dinv^2. Output unscaled.
// PRESCALED=true (layer 2): input rows are already h' = h*dinv[row]
//   (written by gemm1's SCALE_DINV epilogue). out[n] = dinv[n]*(h'[n]+sum h'[src])
//   == dinv^2 h[n] + sum dinv[n]dinv[src] h[src]. No per-edge deg loads,
//   no per-edge rsqrt -> one fewer dependent latency per iteration.

template<int LPN, bool PRESCALED>
__global__ __launch_bounds__(256) void gather_kernel(
    const short* __restrict__ h, const int* __restrict__ deg,
    const int* __restrict__ eslot, short* __restrict__ out, int n)
{
    const int F = LPN * 8;
    int node = (blockIdx.x * 256 + threadIdx.x) / LPN;
    if (node >= n) return;
    int lane = threadIdx.x % LPN;
    int f = lane * 8;

    int dg = deg[node];
    if (dg > CAP) dg = CAP;
    float di = rsqrtf((float)dg + 1.0f);

    const size_t rb = (size_t)node * F + f;
    short8 hv = *(const short8*)(h + rb);
    float a[8];
    const float selfw = PRESCALED ? 1.0f : di * di;
    #pragma unroll
    for (int j = 0; j < 8; ++j) a[j] = bf2f(hv[j]) * selfw;

    const int* bucket = eslot + (size_t)node * CAP;
    for (int e = 0; e < dg; e += 8) {
        int4 sa = *(const int4*)(bucket + e);
        int4 sb = *(const int4*)(bucket + e + 4);   // CAP%8==0: in-bounds
        // guard padding lanes BEFORE any dereference (slots past dg are poison)
        int id[8];
        id[0] = sa.x;
        id[1] = (e + 1 < dg) ? sa.y : 0;
        id[2] = (e + 2 < dg) ? sa.z : 0;
        id[3] = (e + 3 < dg) ? sa.w : 0;
        id[4] = (e + 4 < dg) ? sb.x : 0;
        id[5] = (e + 5 < dg) ? sb.y : 0;
        id[6] = (e + 6 < dg) ? sb.z : 0;
        id[7] = (e + 7 < dg) ? sb.w : 0;

        short8 v[8];
        #pragma unroll
        for (int t = 0; t < 8; ++t)
            v[t] = *(const short8*)(h + (size_t)id[t] * F + f);

        float w[8];
        if (PRESCALED) {
            #pragma unroll
            for (int t = 0; t < 8; ++t)
                w[t] = (e + t < dg) ? 1.0f : 0.0f;
        } else {
            #pragma unroll
            for (int t = 0; t < 8; ++t) {
                float ds = (float)deg[id[t]];
                w[t] = (e + t < dg) ? rsqrtf(ds + 1.0f) * di : 0.0f;
            }
        }

        #pragma unroll
        for (int t = 0; t < 8; ++t)
            #pragma unroll
            for (int j = 0; j < 8; ++j)
                a[j] = fmaf(bf2f(v[t][j]), w[t], a[j]);
    }

    if (PRESCALED) {
        #pragma unroll
        for (int j = 0; j < 8; ++j) a[j] *= di;
    }

    short8 o;
    #pragma unroll
    for (int j = 0; j < 8; ++j) o[j] = f2bf(a[j]);
    *(short8*)(out + rb) = o;
}

// ---------------- launch ----------------

extern "C" void kernel_launch(void* const* d_in, const int* in_sizes, int n_in,
                              void* d_out, int out_size, void* d_ws, size_t ws_size,
                              hipStream_t stream) {
    const float* x  = (const float*)d_in[0];
    const int*   ei = (const int*)d_in[1];
    const float* W1 = (const float*)d_in[2];
    const float* b1 = (const float*)d_in[3];
    const float* W2 = (const float*)d_in[4];
    const float* b2 = (const float*)d_in[5];
    const float* Wc = (const float*)d_in[6];
    const float* bc = (const float*)d_in[7];
    float* out = (float*)d_out;

    const int E = in_sizes[1] / 2;
    const int N = in_sizes[0] / 128;
    const int F_IN = 128, H = 256;
    const int* src = ei;
    const int* dst = ei + E;

    // workspace layout (shorts first, 16B aligned)
    short* xb   = (short*)d_ws;                     // N*128
    short* aggX = xb + (size_t)N * 128;             // N*128
    short* hA   = aggX + (size_t)N * 128;           // N*256
    short* hB   = hA + (size_t)N * 256;             // N*256
    short* Wt1  = hB + (size_t)N * 256;             // 256*128
    short* Wt2  = Wt1 + 256 * 128;                  // 256*256
    short* Wtc  = Wt2 + 256 * 256;                  // 32*256
    int*   deg  = (int*)(Wtc + 32 * 256);           // N
    int*   eslot= deg + N;                          // N*CAP (16B-aligned: N*CAP*4)

    const int TB = 256;

    hipMemsetAsync(deg, 0, (size_t)N * sizeof(int), stream);

    const int prep_total = N * 16 + 128 * 256 + 256 * 256 + 256 * 32 + E;
    prep_kernel<<<(prep_total + TB - 1) / TB, TB, 0, stream>>>(
        x, W1, W2, Wc, src, dst, xb, Wt1, Wt2, Wtc, deg, eslot, N, E);

    const int gy = (N + 127) / 128;

    // layer 1: aggX = A_hat @ X ; hA = relu(aggX @ W1 + b1) * dinv[row]
    gather_kernel<16, false><<<((size_t)N * 16 + TB - 1) / TB, TB, 0, stream>>>(
        xb, deg, eslot, aggX, N);
    mfma_gemm128_kernel<true, true><<<dim3(H / 128, gy), 256, 0, stream>>>(
        aggX, Wt1, b1, hA, deg, N, F_IN, H);

    // layer 2: hB = dinv[n]*(hA'[n] + sum hA'[src]) ; hA = relu(hB @ W2 + b2)
    gather_kernel<32, true><<<((size_t)N * 32 + TB - 1) / TB, TB, 0, stream>>>(
        hA, deg, eslot, hB, N);
    mfma_gemm128_kernel<true, false><<<dim3(H / 128, gy), 256, 0, stream>>>(
        hB, Wt2, b2, hA, deg, N, H, H);

    // classifier: out = hA @ Wc + bc (fp32)
    mfma_gemmc_kernel<<<gy, 128, 0, stream>>>(hA, Wtc, bc, out, N, H);
}

// Round 2
// 235.432 us; speedup vs baseline: 1.0126x; 1.0126x over previous
//
#include <hip/hip_runtime.h>
#include <math.h>

using short8 = __attribute__((ext_vector_type(8))) short;
using f32x4 = __attribute__((ext_vector_type(4))) float;

#define CAP 48   // edge-bucket capacity; P(Poisson(6) >= 48) ~ 1e-30

__device__ inline short f2bf(float f) {
    unsigned u = __builtin_bit_cast(unsigned, f);
    unsigned r = (u + 0x7fffu + ((u >> 16) & 1u)) >> 16;
    return (short)r;
}
__device__ inline float bf2f(short s) {
    unsigned u = ((unsigned)(unsigned short)s) << 16;
    return __builtin_bit_cast(float, u);
}

// ---------------- fused prep: x->bf16, W transposes, edge bucketing ----------------
// deg[] and eslot[] must be zeroed (one merged memsetAsync) before this kernel.
// Zeroed eslot => padding slots hold node index 0 (valid row), so the gather
// never needs index guards, only weight guards.

__global__ void prep_kernel(const float* __restrict__ x, const float* __restrict__ W1,
                            const float* __restrict__ W2, const float* __restrict__ Wc,
                            const int* __restrict__ src, const int* __restrict__ dst,
                            short* __restrict__ xb, short* __restrict__ Wt1,
                            short* __restrict__ Wt2, short* __restrict__ Wtc,
                            int* __restrict__ deg, int* __restrict__ eslot,
                            int n, int e) {
    int idx = blockIdx.x * blockDim.x + threadIdx.x;
    const int nx8 = n * 16;                      // N*128/8 groups of 8
    if (idx < nx8) {
        const float4* p = (const float4*)x + (size_t)idx * 2;
        float4 v0 = p[0], v1 = p[1];
        short8 o;
        o[0] = f2bf(v0.x); o[1] = f2bf(v0.y); o[2] = f2bf(v0.z); o[3] = f2bf(v0.w);
        o[4] = f2bf(v1.x); o[5] = f2bf(v1.y); o[6] = f2bf(v1.z); o[7] = f2bf(v1.w);
        ((short8*)xb)[idx] = o;
        return;
    }
    idx -= nx8;
    if (idx < 128 * 256) {                       // W1: K=128, N=256
        int k = idx >> 8, c = idx & 255;
        Wt1[c * 128 + k] = f2bf(W1[idx]);
        return;
    }
    idx -= 128 * 256;
    if (idx < 256 * 256) {                       // W2: K=256, N=256
        int k = idx >> 8, c = idx & 255;
        Wt2[c * 256 + k] = f2bf(W2[idx]);
        return;
    }
    idx -= 256 * 256;
    if (idx < 256 * 32) {                        // Wc: K=256, N=32
        int k = idx >> 5, c = idx & 31;
        Wtc[c * 256 + k] = f2bf(Wc[idx]);
        return;
    }
    idx -= 256 * 32;
    if (idx < e) {                               // edge bucketing
        int d = dst[idx], s = src[idx];
        int pos = atomicAdd(&deg[d], 1);
        if (pos < CAP) eslot[(size_t)d * CAP + pos] = s;
    }
}

// ---------------- dinv table: dinvt[i] = rsqrt(deg[i]+1) ----------------
// Lets gather-1 load the neighbor's norm factor at the SAME chain depth as
// the neighbor row (both depend only on the bucket id), instead of
// bucket -> deg[id] -> rsqrt -> fma (one extra dependent latency).

__global__ void dinv_kernel(const int* __restrict__ deg, float* __restrict__ dinvt, int n) {
    int i = blockIdx.x * blockDim.x + threadIdx.x;
    if (i < n) dinvt[i] = rsqrtf((float)deg[i] + 1.0f);
}

// ---------------- bf16 MFMA GEMM 128x128 ----------------
// 4 waves; wave computes 64x64 via 4x4 of 16x16x32 MFMAs. LDS rows padded
// to 40 shorts (80B) -> max 2-way bank aliasing (free).
// SCALE_DINV: multiply the (relu'd) output row by rsqrt(deg[row]+1) so the
// next gather can be a pure unweighted sum (symmetric-norm pre-scaling).

template<bool RELU_BF16OUT, bool SCALE_DINV>
__global__ __launch_bounds__(256) void mfma_gemm128_kernel(
    const short* __restrict__ A, const short* __restrict__ Wt,
    const float* __restrict__ bias, void* __restrict__ Cout,
    const int* __restrict__ deg,
    int M, int K, int NC)
{
    __shared__ short As[128 * 40];
    __shared__ short Bs[128 * 40];

    const int tid = threadIdx.x;
    const int wave = tid >> 6, lane = tid & 63;
    const int m0 = blockIdx.y * 128, n0 = blockIdx.x * 128;
    const int wm = (wave >> 1) * 64, wn = (wave & 1) * 64;

    const int sar = tid >> 2;
    const int sak = (tid & 3) * 8;
    int ga0 = m0 + sar;      if (ga0 >= M) ga0 = M - 1;
    int ga1 = m0 + 64 + sar; if (ga1 >= M) ga1 = M - 1;
    int gb0 = n0 + sar;      if (gb0 >= NC) gb0 = NC - 1;
    int gb1 = n0 + 64 + sar; if (gb1 >= NC) gb1 = NC - 1;
    const short* pa0 = A + (size_t)ga0 * K + sak;
    const short* pa1 = A + (size_t)ga1 * K + sak;
    const short* pb0 = Wt + (size_t)gb0 * K + sak;
    const short* pb1 = Wt + (size_t)gb1 * K + sak;

    const int lw0 = sar * 40 + sak;
    const int lw1 = (64 + sar) * 40 + sak;

    f32x4 acc[4][4] = {};
    const int fr = lane & 15;
    const int fk = (lane >> 4) * 8;

    for (int k0 = 0; k0 < K; k0 += 32) {
        short8 va0 = *(const short8*)(pa0 + k0);
        short8 va1 = *(const short8*)(pa1 + k0);
        short8 vb0 = *(const short8*)(pb0 + k0);
        short8 vb1 = *(const short8*)(pb1 + k0);
        __syncthreads();
        *(short8*)&As[lw0] = va0;
        *(short8*)&As[lw1] = va1;
        *(short8*)&Bs[lw0] = vb0;
        *(short8*)&Bs[lw1] = vb1;
        __syncthreads();

        short8 af[4], bfv[4];
        #pragma unroll
        for (int mt = 0; mt < 4; ++mt)
            af[mt] = *(const short8*)&As[(wm + mt * 16 + fr) * 40 + fk];
        #pragma unroll
        for (int nt = 0; nt < 4; ++nt)
            bfv[nt] = *(const short8*)&Bs[(wn + nt * 16 + fr) * 40 + fk];

        #pragma unroll
        for (int mt = 0; mt < 4; ++mt)
            #pragma unroll
            for (int nt = 0; nt < 4; ++nt)
                acc[mt][nt] = __builtin_amdgcn_mfma_f32_16x16x32_bf16(
                    af[mt], bfv[nt], acc[mt][nt], 0, 0, 0);
    }

    #pragma unroll
    for (int mt = 0; mt < 4; ++mt) {
        #pragma unroll
        for (int r = 0; r < 4; ++r) {
            int grow = m0 + wm + mt * 16 + (lane >> 4) * 4 + r;
            if (grow >= M) continue;
            float rowscale = 1.0f;
            if (SCALE_DINV)
                rowscale = rsqrtf((float)deg[grow] + 1.0f);
            #pragma unroll
            for (int nt = 0; nt < 4; ++nt) {
                int gcol = n0 + wn + nt * 16 + (lane & 15);
                if (gcol < NC) {
                    float v = acc[mt][nt][r] + bias[gcol];
                    if (RELU_BF16OUT)
                        ((short*)Cout)[(size_t)grow * NC + gcol] =
                            f2bf(fmaxf(v, 0.f) * rowscale);
                    else
                        ((float*)Cout)[(size_t)grow * NC + gcol] = v;
                }
            }
        }
    }
}

// ---------------- classifier GEMM: 128x32 block, 2 waves, NC=32 ----------------

__global__ __launch_bounds__(128) void mfma_gemmc_kernel(
    const short* __restrict__ A, const short* __restrict__ Wt,
    const float* __restrict__ bias, float* __restrict__ Cout,
    int M, int K)
{
    const int NC = 32;
    __shared__ short As[128 * 40];
    __shared__ short Bs[32 * 40];

    const int tid = threadIdx.x;
    const int wave = tid >> 6, lane = tid & 63;
    const int m0 = blockIdx.x * 128;
    const int wm = wave * 64;

    const int sar = tid >> 2;          // 0..31
    const int sak = (tid & 3) * 8;
    int gr0 = m0 + sar;       if (gr0 >= M) gr0 = M - 1;
    int gr1 = m0 + 32 + sar;  if (gr1 >= M) gr1 = M - 1;
    int gr2 = m0 + 64 + sar;  if (gr2 >= M) gr2 = M - 1;
    int gr3 = m0 + 96 + sar;  if (gr3 >= M) gr3 = M - 1;
    const short* pa0 = A + (size_t)gr0 * K + sak;
    const short* pa1 = A + (size_t)gr1 * K + sak;
    const short* pa2 = A + (size_t)gr2 * K + sak;
    const short* pa3 = A + (size_t)gr3 * K + sak;
    const short* pb  = Wt + (size_t)sar * K + sak;

    f32x4 acc[4][2] = {};
    const int fr = lane & 15;
    const int fk = (lane >> 4) * 8;

    for (int k0 = 0; k0 < K; k0 += 32) {
        short8 va0 = *(const short8*)(pa0 + k0);
        short8 va1 = *(const short8*)(pa1 + k0);
        short8 va2 = *(const short8*)(pa2 + k0);
        short8 va3 = *(const short8*)(pa3 + k0);
        short8 vb  = *(const short8*)(pb + k0);
        __syncthreads();
        *(short8*)&As[(sar)       * 40 + sak] = va0;
        *(short8*)&As[(32 + sar)  * 40 + sak] = va1;
        *(short8*)&As[(64 + sar)  * 40 + sak] = va2;
        *(short8*)&As[(96 + sar)  * 40 + sak] = va3;
        *(short8*)&Bs[sar * 40 + sak] = vb;
        __syncthreads();

        short8 af[4], bfv[2];
        #pragma unroll
        for (int mt = 0; mt < 4; ++mt)
            af[mt] = *(const short8*)&As[(wm + mt * 16 + fr) * 40 + fk];
        #pragma unroll
        for (int nt = 0; nt < 2; ++nt)
            bfv[nt] = *(const short8*)&Bs[(nt * 16 + fr) * 40 + fk];

        #pragma unroll
        for (int mt = 0; mt < 4; ++mt)
            #pragma unroll
            for (int nt = 0; nt < 2; ++nt)
                acc[mt][nt] = __builtin_amdgcn_mfma_f32_16x16x32_bf16(
                    af[mt], bfv[nt], acc[mt][nt], 0, 0, 0);
    }

    #pragma unroll
    for (int mt = 0; mt < 4; ++mt) {
        #pragma unroll
        for (int nt = 0; nt < 2; ++nt) {
            #pragma unroll
            for (int r = 0; r < 4; ++r) {
                int grow = m0 + wm + mt * 16 + (lane >> 4) * 4 + r;
                int gcol = nt * 16 + (lane & 15);
                if (grow < M)
                    Cout[(size_t)grow * NC + gcol] = acc[mt][nt][r] + bias[gcol];
            }
        }
    }
}

// ---------------- bucket gather, latency-chain-minimized ----------------
// LPN lanes per node, 8 feats (16B) per lane.
//
// Chain structure: bucket slots 0..15, the self row, and deg[node] all issue
// at entry with NO mutual dependencies (eslot is pre-zeroed, so slot ids are
// always valid rows -> no index guards, no dependence of loads on deg).
// Round 0 (slots 0..7, covers ~84% of nodes fully) row loads depend only on
// the bucket data: critical path = bucket -> rows = 2 memory latencies.
// deg only gates WEIGHTS (cndmask) and the final *di scale.
//
// PRESCALED=false (layer 1): edge weight = dinvt[src] (gathered at same
//   depth as the row load); whole sum scaled by di at the end; self term
//   contributes hv*di before that scale -> di^2*hv + sum di*dinv_src*h_src.
// PRESCALED=true (layer 2): rows already scaled by their own dinv (gemm1
//   epilogue); weights are 1/0; out = di*(hv + sum h'_src).

template<int LPN, bool PRESCALED>
__global__ __launch_bounds__(256) void gather_kernel(
    const short* __restrict__ h, const int* __restrict__ deg,
    const float* __restrict__ dinvt, const int* __restrict__ eslot,
    short* __restrict__ out, int n)
{
    const int F = LPN * 8;
    int node = (blockIdx.x * 256 + threadIdx.x) / LPN;
    if (node >= n) return;
    int lane = threadIdx.x % LPN;
    int f = lane * 8;

    // --- all launch-independent loads issue first ---
    const int* bucket = eslot + (size_t)node * CAP;
    int4 sa = *(const int4*)(bucket + 0);
    int4 sb = *(const int4*)(bucket + 4);
    int4 sc = *(const int4*)(bucket + 8);
    int4 sd = *(const int4*)(bucket + 12);
    const size_t rb = (size_t)node * F + f;
    short8 hv = *(const short8*)(h + rb);
    int dg = deg[node];
    if (dg > CAP) dg = CAP;

    // --- round 0: slots 0..7, unconditional (padding = row 0, weight 0) ---
    int i0[8] = {sa.x, sa.y, sa.z, sa.w, sb.x, sb.y, sb.z, sb.w};
    short8 v0[8];
    #pragma unroll
    for (int t = 0; t < 8; ++t)
        v0[t] = *(const short8*)(h + (size_t)i0[t] * F + f);

    float w0[8];
    #pragma unroll
    for (int t = 0; t < 8; ++t)
        w0[t] = (t < dg) ? (PRESCALED ? 1.0f : dinvt[i0[t]]) : 0.0f;

    float a[8] = {};
    #pragma unroll
    for (int t = 0; t < 8; ++t)
        #pragma unroll
        for (int j = 0; j < 8; ++j)
            a[j] = fmaf(bf2f(v0[t][j]), w0[t], a[j]);

    // --- round 1: slots 8..15 (16% of nodes) ---
    if (dg > 8) {
        int i1[8] = {sc.x, sc.y, sc.z, sc.w, sd.x, sd.y, sd.z, sd.w};
        short8 v1[8];
        #pragma unroll
        for (int t = 0; t < 8; ++t)
            v1[t] = *(const short8*)(h + (size_t)i1[t] * F + f);
        float w1[8];
        #pragma unroll
        for (int t = 0; t < 8; ++t)
            w1[t] = (8 + t < dg) ? (PRESCALED ? 1.0f : dinvt[i1[t]]) : 0.0f;
        #pragma unroll
        for (int t = 0; t < 8; ++t)
            #pragma unroll
            for (int j = 0; j < 8; ++j)
                a[j] = fmaf(bf2f(v1[t][j]), w1[t], a[j]);

        // --- rare tail: deg > 16 (P ~ 2.5e-4) ---
        for (int e = 16; e < dg; e += 8) {
            int4 se = *(const int4*)(bucket + e);
            int4 sf = *(const int4*)(bucket + e + 4);   // e<=40, CAP=48: in-bounds
            int i2[8] = {se.x, se.y, se.z, se.w, sf.x, sf.y, sf.z, sf.w};
            short8 v2[8];
            #pragma unroll
            for (int t = 0; t < 8; ++t)
                v2[t] = *(const short8*)(h + (size_t)i2[t] * F + f);
            float w2[8];
            #pragma unroll
            for (int t = 0; t < 8; ++t)
                w2[t] = (e + t < dg) ? (PRESCALED ? 1.0f : dinvt[i2[t]]) : 0.0f;
            #pragma unroll
            for (int t = 0; t < 8; ++t)
                #pragma unroll
                for (int j = 0; j < 8; ++j)
                    a[j] = fmaf(bf2f(v2[t][j]), w2[t], a[j]);
        }
    }

    // --- self term + final scale (deg-dependent, off the load path) ---
    float di = rsqrtf((float)dg + 1.0f);
    const float selfw = PRESCALED ? 1.0f : di;
    short8 o;
    #pragma unroll
    for (int j = 0; j < 8; ++j)
        o[j] = f2bf(fmaf(bf2f(hv[j]), selfw, a[j]) * di);
    *(short8*)(out + rb) = o;
}

// ---------------- launch ----------------

extern "C" void kernel_launch(void* const* d_in, const int* in_sizes, int n_in,
                              void* d_out, int out_size, void* d_ws, size_t ws_size,
                              hipStream_t stream) {
    const float* x  = (const float*)d_in[0];
    const int*   ei = (const int*)d_in[1];
    const float* W1 = (const float*)d_in[2];
    const float* b1 = (const float*)d_in[3];
    const float* W2 = (const float*)d_in[4];
    const float* b2 = (const float*)d_in[5];
    const float* Wc = (const float*)d_in[6];
    const float* bc = (const float*)d_in[7];
    float* out = (float*)d_out;

    const int E = in_sizes[1] / 2;
    const int N = in_sizes[0] / 128;
    const int F_IN = 128, H = 256;
    const int* src = ei;
    const int* dst = ei + E;

    // workspace layout (shorts first, 16B aligned)
    short* xb   = (short*)d_ws;                     // N*128
    short* aggX = xb + (size_t)N * 128;             // N*128
    short* hA   = aggX + (size_t)N * 128;           // N*256
    short* hB   = hA + (size_t)N * 256;             // N*256
    short* Wt1  = hB + (size_t)N * 256;             // 256*128
    short* Wt2  = Wt1 + 256 * 128;                  // 256*256
    short* Wtc  = Wt2 + 256 * 256;                  // 32*256
    int*   deg  = (int*)(Wtc + 32 * 256);           // N
    int*   eslot= deg + N;                          // N*CAP
    float* dinvt= (float*)(eslot + (size_t)N * CAP);// N

    const int TB = 256;

    // one merged memset: deg (N ints) + eslot (N*CAP ints) are contiguous
    hipMemsetAsync(deg, 0, (size_t)N * (CAP + 1) * sizeof(int), stream);

    const int prep_total = N * 16 + 128 * 256 + 256 * 256 + 256 * 32 + E;
    prep_kernel<<<(prep_total + TB - 1) / TB, TB, 0, stream>>>(
        x, W1, W2, Wc, src, dst, xb, Wt1, Wt2, Wtc, deg, eslot, N, E);

    dinv_kernel<<<(N + TB - 1) / TB, TB, 0, stream>>>(deg, dinvt, N);

    const int gy = (N + 127) / 128;

    // layer 1: aggX = A_hat @ X ; hA = relu(aggX @ W1 + b1) * dinv[row]
    gather_kernel<16, false><<<((size_t)N * 16 + TB - 1) / TB, TB, 0, stream>>>(
        xb, deg, dinvt, eslot, aggX, N);
    mfma_gemm128_kernel<true, true><<<dim3(H / 128, gy), 256, 0, stream>>>(
        aggX, Wt1, b1, hA, deg, N, F_IN, H);

    // layer 2: hB = dinv[n]*(hA'[n] + sum hA'[src]) ; hA = relu(hB @ W2 + b2)
    gather_kernel<32, true><<<((size_t)N * 32 + TB - 1) / TB, TB, 0, stream>>>(
        hA, deg, dinvt, eslot, hB, N);
    mfma_gemm128_kernel<true, false><<<dim3(H / 128, gy), 256, 0, stream>>>(
        hB, Wt2, b2, hA, deg, N, H, H);

    // classifier: out = hA @ Wc + bc (fp32)
    mfma_gemmc_kernel<<<gy, 128, 0, stream>>>(hA, Wtc, bc, out, N, H);
}

// Round 3
// 230.046 us; speedup vs baseline: 1.0363x; 1.0234x over previous
//
#include <hip/hip_runtime.h>
#include <math.h>

using short8 = __attribute__((ext_vector_type(8))) short;
using f32x4 = __attribute__((ext_vector_type(4))) float;

#define CAP 48   // edge-bucket capacity; P(Poisson(6) >= 48) ~ 1e-30

__device__ inline short f2bf(float f) {
    unsigned u = __builtin_bit_cast(unsigned, f);
    unsigned r = (u + 0x7fffu + ((u >> 16) & 1u)) >> 16;
    return (short)r;
}
__device__ inline float bf2f(short s) {
    unsigned u = ((unsigned)(unsigned short)s) << 16;
    return __builtin_bit_cast(float, u);
}

// ---------------- fused prep: x->bf16, W transposes, edge bucketing ----------------
// deg[] and eslot[] must be zeroed (one merged memsetAsync) before this kernel.
// Zeroed eslot => padding slots hold node index 0 (a valid row), so the gather
// needs no index guards, only weight guards.

__global__ void prep_kernel(const float* __restrict__ x, const float* __restrict__ W1,
                            const float* __restrict__ W2, const float* __restrict__ Wc,
                            const int* __restrict__ src, const int* __restrict__ dst,
                            short* __restrict__ xb, short* __restrict__ Wt1,
                            short* __restrict__ Wt2, short* __restrict__ Wtc,
                            int* __restrict__ deg, int* __restrict__ eslot,
                            int n, int e) {
    int idx = blockIdx.x * blockDim.x + threadIdx.x;
    const int nx8 = n * 16;                      // N*128/8 groups of 8
    if (idx < nx8) {
        const float4* p = (const float4*)x + (size_t)idx * 2;
        float4 v0 = p[0], v1 = p[1];
        short8 o;
        o[0] = f2bf(v0.x); o[1] = f2bf(v0.y); o[2] = f2bf(v0.z); o[3] = f2bf(v0.w);
        o[4] = f2bf(v1.x); o[5] = f2bf(v1.y); o[6] = f2bf(v1.z); o[7] = f2bf(v1.w);
        ((short8*)xb)[idx] = o;
        return;
    }
    idx -= nx8;
    if (idx < 128 * 256) {                       // W1: K=128, N=256
        int k = idx >> 8, c = idx & 255;
        Wt1[c * 128 + k] = f2bf(W1[idx]);
        return;
    }
    idx -= 128 * 256;
    if (idx < 256 * 256) {                       // W2: K=256, N=256
        int k = idx >> 8, c = idx & 255;
        Wt2[c * 256 + k] = f2bf(W2[idx]);
        return;
    }
    idx -= 256 * 256;
    if (idx < 256 * 32) {                        // Wc: K=256, N=32
        int k = idx >> 5, c = idx & 31;
        Wtc[c * 256 + k] = f2bf(Wc[idx]);
        return;
    }
    idx -= 256 * 32;
    if (idx < e) {                               // edge bucketing
        int d = dst[idx], s = src[idx];
        int pos = atomicAdd(&deg[d], 1);
        if (pos < CAP) eslot[(size_t)d * CAP + pos] = s;
    }
}

// ---------------- dinv table: dinvt[i] = rsqrt(deg[i]+1) ----------------

__global__ void dinv_kernel(const int* __restrict__ deg, float* __restrict__ dinvt, int n) {
    int i = blockIdx.x * blockDim.x + threadIdx.x;
    if (i < n) dinvt[i] = rsqrtf((float)deg[i] + 1.0f);
}

// ---------------- bf16 MFMA GEMM 128x128 ----------------
// 4 waves; wave computes 64x64 via 4x4 of 16x16x32 MFMAs. LDS rows padded
// to 40 shorts (80B) -> max 2-way bank aliasing (free).
// SCALE_DINV: multiply the (relu'd) output row by dinvt[row] so the next
// gather can be a pure unweighted sum (symmetric-norm pre-scaling).

template<bool RELU_BF16OUT, bool SCALE_DINV>
__global__ __launch_bounds__(256) void mfma_gemm128_kernel(
    const short* __restrict__ A, const short* __restrict__ Wt,
    const float* __restrict__ bias, void* __restrict__ Cout,
    const float* __restrict__ dinvt,
    int M, int K, int NC)
{
    __shared__ short As[128 * 40];
    __shared__ short Bs[128 * 40];

    const int tid = threadIdx.x;
    const int wave = tid >> 6, lane = tid & 63;
    const int m0 = blockIdx.y * 128, n0 = blockIdx.x * 128;
    const int wm = (wave >> 1) * 64, wn = (wave & 1) * 64;

    const int sar = tid >> 2;
    const int sak = (tid & 3) * 8;
    int ga0 = m0 + sar;      if (ga0 >= M) ga0 = M - 1;
    int ga1 = m0 + 64 + sar; if (ga1 >= M) ga1 = M - 1;
    int gb0 = n0 + sar;      if (gb0 >= NC) gb0 = NC - 1;
    int gb1 = n0 + 64 + sar; if (gb1 >= NC) gb1 = NC - 1;
    const short* pa0 = A + (size_t)ga0 * K + sak;
    const short* pa1 = A + (size_t)ga1 * K + sak;
    const short* pb0 = Wt + (size_t)gb0 * K + sak;
    const short* pb1 = Wt + (size_t)gb1 * K + sak;

    const int lw0 = sar * 40 + sak;
    const int lw1 = (64 + sar) * 40 + sak;

    f32x4 acc[4][4] = {};
    const int fr = lane & 15;
    const int fk = (lane >> 4) * 8;

    for (int k0 = 0; k0 < K; k0 += 32) {
        short8 va0 = *(const short8*)(pa0 + k0);
        short8 va1 = *(const short8*)(pa1 + k0);
        short8 vb0 = *(const short8*)(pb0 + k0);
        short8 vb1 = *(const short8*)(pb1 + k0);
        __syncthreads();
        *(short8*)&As[lw0] = va0;
        *(short8*)&As[lw1] = va1;
        *(short8*)&Bs[lw0] = vb0;
        *(short8*)&Bs[lw1] = vb1;
        __syncthreads();

        short8 af[4], bfv[4];
        #pragma unroll
        for (int mt = 0; mt < 4; ++mt)
            af[mt] = *(const short8*)&As[(wm + mt * 16 + fr) * 40 + fk];
        #pragma unroll
        for (int nt = 0; nt < 4; ++nt)
            bfv[nt] = *(const short8*)&Bs[(wn + nt * 16 + fr) * 40 + fk];

        #pragma unroll
        for (int mt = 0; mt < 4; ++mt)
            #pragma unroll
            for (int nt = 0; nt < 4; ++nt)
                acc[mt][nt] = __builtin_amdgcn_mfma_f32_16x16x32_bf16(
                    af[mt], bfv[nt], acc[mt][nt], 0, 0, 0);
    }

    #pragma unroll
    for (int mt = 0; mt < 4; ++mt) {
        #pragma unroll
        for (int r = 0; r < 4; ++r) {
            int grow = m0 + wm + mt * 16 + (lane >> 4) * 4 + r;
            if (grow >= M) continue;
            float rowscale = 1.0f;
            if (SCALE_DINV)
                rowscale = dinvt[grow];
            #pragma unroll
            for (int nt = 0; nt < 4; ++nt) {
                int gcol = n0 + wn + nt * 16 + (lane & 15);
                if (gcol < NC) {
                    float v = acc[mt][nt][r] + bias[gcol];
                    if (RELU_BF16OUT)
                        ((short*)Cout)[(size_t)grow * NC + gcol] =
                            f2bf(fmaxf(v, 0.f) * rowscale);
                    else
                        ((float*)Cout)[(size_t)grow * NC + gcol] = v;
                }
            }
        }
    }
}

// ---------------- classifier GEMM: 128x32 block, 2 waves, NC=32 ----------------

__global__ __launch_bounds__(128) void mfma_gemmc_kernel(
    const short* __restrict__ A, const short* __restrict__ Wt,
    const float* __restrict__ bias, float* __restrict__ Cout,
    int M, int K)
{
    const int NC = 32;
    __shared__ short As[128 * 40];
    __shared__ short Bs[32 * 40];

    const int tid = threadIdx.x;
    const int wave = tid >> 6, lane = tid & 63;
    const int m0 = blockIdx.x * 128;
    const int wm = wave * 64;

    const int sar = tid >> 2;          // 0..31
    const int sak = (tid & 3) * 8;
    int gr0 = m0 + sar;       if (gr0 >= M) gr0 = M - 1;
    int gr1 = m0 + 32 + sar;  if (gr1 >= M) gr1 = M - 1;
    int gr2 = m0 + 64 + sar;  if (gr2 >= M) gr2 = M - 1;
    int gr3 = m0 + 96 + sar;  if (gr3 >= M) gr3 = M - 1;
    const short* pa0 = A + (size_t)gr0 * K + sak;
    const short* pa1 = A + (size_t)gr1 * K + sak;
    const short* pa2 = A + (size_t)gr2 * K + sak;
    const short* pa3 = A + (size_t)gr3 * K + sak;
    const short* pb  = Wt + (size_t)sar * K + sak;

    f32x4 acc[4][2] = {};
    const int fr = lane & 15;
    const int fk = (lane >> 4) * 8;

    for (int k0 = 0; k0 < K; k0 += 32) {
        short8 va0 = *(const short8*)(pa0 + k0);
        short8 va1 = *(const short8*)(pa1 + k0);
        short8 va2 = *(const short8*)(pa2 + k0);
        short8 va3 = *(const short8*)(pa3 + k0);
        short8 vb  = *(const short8*)(pb + k0);
        __syncthreads();
        *(short8*)&As[(sar)       * 40 + sak] = va0;
        *(short8*)&As[(32 + sar)  * 40 + sak] = va1;
        *(short8*)&As[(64 + sar)  * 40 + sak] = va2;
        *(short8*)&As[(96 + sar)  * 40 + sak] = va3;
        *(short8*)&Bs[sar * 40 + sak] = vb;
        __syncthreads();

        short8 af[4], bfv[2];
        #pragma unroll
        for (int mt = 0; mt < 4; ++mt)
            af[mt] = *(const short8*)&As[(wm + mt * 16 + fr) * 40 + fk];
        #pragma unroll
        for (int nt = 0; nt < 2; ++nt)
            bfv[nt] = *(const short8*)&Bs[(nt * 16 + fr) * 40 + fk];

        #pragma unroll
        for (int mt = 0; mt < 4; ++mt)
            #pragma unroll
            for (int nt = 0; nt < 2; ++nt)
                acc[mt][nt] = __builtin_amdgcn_mfma_f32_16x16x32_bf16(
                    af[mt], bfv[nt], acc[mt][nt], 0, 0, 0);
    }

    #pragma unroll
    for (int mt = 0; mt < 4; ++mt) {
        #pragma unroll
        for (int nt = 0; nt < 2; ++nt) {
            #pragma unroll
            for (int r = 0; r < 4; ++r) {
                int grow = m0 + wm + mt * 16 + (lane >> 4) * 4 + r;
                int gcol = nt * 16 + (lane & 15);
                if (grow < M)
                    Cout[(size_t)grow * NC + gcol] = acc[mt][nt][r] + bias[gcol];
            }
        }
    }
}

// ---------------- bucket gather: round-0 4-wide loop shape (low VGPR) ----------------
// LPN lanes per node, 8 feats (16B) per lane. Edges in ceil(deg/4) quads.
// Occupancy is the latency-hiding mechanism here (R1/R2 lesson: wider
// unrolls raise VGPRs, cut waves/SIMD, and regress). Kept changes vs round 0:
//  - no index guards (eslot pre-zeroed; padding slot -> row 0, weight 0)
//  - PRESCALED=false (layer 1): weight = dinvt[src] (parallel 4B load, no
//    dependent convert+rsqrt); out = di*(di*hv + sum dinvt[src]*h_src)
//  - PRESCALED=true (layer 2): rows pre-scaled by their own dinv in gemm1's
//    epilogue; no weight loads at all; out = di*(hv + sum h'_src)

template<int LPN, bool PRESCALED>
__global__ __launch_bounds__(256) void gather_kernel(
    const short* __restrict__ h, const int* __restrict__ deg,
    const float* __restrict__ dinvt, const int* __restrict__ eslot,
    short* __restrict__ out, int n)
{
    const int F = LPN * 8;
    int node = (blockIdx.x * 256 + threadIdx.x) / LPN;
    if (node >= n) return;
    int lane = threadIdx.x % LPN;
    int f = lane * 8;

    int dg = deg[node];
    if (dg > CAP) dg = CAP;

    const size_t rb = (size_t)node * F + f;
    short8 hv = *(const short8*)(h + rb);
    float a[8] = {};

    const int* bucket = eslot + (size_t)node * CAP;
    for (int e = 0; e < dg; e += 4) {
        int4 s4 = *(const int4*)(bucket + e);
        // no index guards: padding slots hold 0 (valid row); weights mask them
        short8 v0 = *(const short8*)(h + (size_t)s4.x * F + f);
        short8 v1 = *(const short8*)(h + (size_t)s4.y * F + f);
        short8 v2 = *(const short8*)(h + (size_t)s4.z * F + f);
        short8 v3 = *(const short8*)(h + (size_t)s4.w * F + f);
        float w0, w1, w2, w3;
        if (PRESCALED) {
            w0 = 1.0f;
            w1 = (e + 1 < dg) ? 1.0f : 0.0f;
            w2 = (e + 2 < dg) ? 1.0f : 0.0f;
            w3 = (e + 3 < dg) ? 1.0f : 0.0f;
        } else {
            w0 = dinvt[s4.x];
            w1 = (e + 1 < dg) ? dinvt[s4.y] : 0.0f;
            w2 = (e + 2 < dg) ? dinvt[s4.z] : 0.0f;
            w3 = (e + 3 < dg) ? dinvt[s4.w] : 0.0f;
        }
        #pragma unroll
        for (int j = 0; j < 8; ++j) {
            a[j] = fmaf(bf2f(v0[j]), w0, a[j]);
            a[j] = fmaf(bf2f(v1[j]), w1, a[j]);
            a[j] = fmaf(bf2f(v2[j]), w2, a[j]);
            a[j] = fmaf(bf2f(v3[j]), w3, a[j]);
        }
    }

    // self term + final scale (off the load path)
    float di = rsqrtf((float)dg + 1.0f);
    const float selfw = PRESCALED ? 1.0f : di;
    short8 o;
    #pragma unroll
    for (int j = 0; j < 8; ++j)
        o[j] = f2bf(fmaf(bf2f(hv[j]), selfw, a[j]) * di);
    *(short8*)(out + rb) = o;
}

// ---------------- launch ----------------

extern "C" void kernel_launch(void* const* d_in, const int* in_sizes, int n_in,
                              void* d_out, int out_size, void* d_ws, size_t ws_size,
                              hipStream_t stream) {
    const float* x  = (const float*)d_in[0];
    const int*   ei = (const int*)d_in[1];
    const float* W1 = (const float*)d_in[2];
    const float* b1 = (const float*)d_in[3];
    const float* W2 = (const float*)d_in[4];
    const float* b2 = (const float*)d_in[5];
    const float* Wc = (const float*)d_in[6];
    const float* bc = (const float*)d_in[7];
    float* out = (float*)d_out;

    const int E = in_sizes[1] / 2;
    const int N = in_sizes[0] / 128;
    const int F_IN = 128, H = 256;
    const int* src = ei;
    const int* dst = ei + E;

    // workspace layout (shorts first, 16B aligned)
    short* xb   = (short*)d_ws;                     // N*128
    short* aggX = xb + (size_t)N * 128;             // N*128
    short* hA   = aggX + (size_t)N * 128;           // N*256
    short* hB   = hA + (size_t)N * 256;             // N*256
    short* Wt1  = hB + (size_t)N * 256;             // 256*128
    short* Wt2  = Wt1 + 256 * 128;                  // 256*256
    short* Wtc  = Wt2 + 256 * 256;                  // 32*256
    int*   deg  = (int*)(Wtc + 32 * 256);           // N
    int*   eslot= deg + N;                          // N*CAP
    float* dinvt= (float*)(eslot + (size_t)N * CAP);// N

    const int TB = 256;

    // one merged memset: deg (N ints) + eslot (N*CAP ints) are contiguous
    hipMemsetAsync(deg, 0, (size_t)N * (CAP + 1) * sizeof(int), stream);

    const int prep_total = N * 16 + 128 * 256 + 256 * 256 + 256 * 32 + E;
    prep_kernel<<<(prep_total + TB - 1) / TB, TB, 0, stream>>>(
        x, W1, W2, Wc, src, dst, xb, Wt1, Wt2, Wtc, deg, eslot, N, E);

    dinv_kernel<<<(N + TB - 1) / TB, TB, 0, stream>>>(deg, dinvt, N);

    const int gy = (N + 127) / 128;

    // layer 1: aggX = A_hat @ X ; hA = relu(aggX @ W1 + b1) * dinv[row]
    gather_kernel<16, false><<<((size_t)N * 16 + TB - 1) / TB, TB, 0, stream>>>(
        xb, deg, dinvt, eslot, aggX, N);
    mfma_gemm128_kernel<true, true><<<dim3(H / 128, gy), 256, 0, stream>>>(
        aggX, Wt1, b1, hA, dinvt, N, F_IN, H);

    // layer 2: hB = dinv[n]*(hA'[n] + sum hA'[src]) ; hA = relu(hB @ W2 + b2)
    gather_kernel<32, true><<<((size_t)N * 32 + TB - 1) / TB, TB, 0, stream>>>(
        hA, deg, dinvt, eslot, hB, N);
    mfma_gemm128_kernel<true, false><<<dim3(H / 128, gy), 256, 0, stream>>>(
        hB, Wt2, b2, hA, dinvt, N, H, H);

    // classifier: out = hA @ Wc + bc (fp32)
    mfma_gemmc_kernel<<<gy, 128, 0, stream>>>(hA, Wtc, bc, out, N, H);
}